// Round 7
// baseline (271.557 us; speedup 1.0000x reference)
//
#include <hip/hip_runtime.h>
#include <hip/hip_bf16.h>

typedef unsigned short u16;
typedef unsigned char u8;
typedef float f32x4 __attribute__((ext_vector_type(4)));
typedef int int4v __attribute__((ext_vector_type(4)));
typedef int int8v __attribute__((ext_vector_type(8)));

#define B_ROWS 8192
#define D_DIM  1024
#define FP8_SCALE 16.0f          // store x*16 in e4m3; acc = 256 * s_true
#define ACC_UNSCALE (1.0f/256.0f)

// ---------------------------------------------------------------------------
// Workspace layout (bytes):
//   [0,      32768)   ppq[8192]   per-row MSE(q) partial
//   [32768,  65536)   ppp[8192]   per-row MSE(p) partial
//   [65536,  98304)   ppd[8192]   per-row diag cosine (exact fp32)
//   [98304,  98816)   bpart[32][4] per-reduce-block partials
//   [131072, +4MiB)   gpart[128][8192]  per-64-col-slice row exp-sum partials
//   [+4MiB,  +8MiB)   qn fp8 [8192][1024]   (x16 pre-scaled e4m3)
//   [+8MiB,  ...)     pn fp8 [8192][1024]
// ---------------------------------------------------------------------------

// ---------------------------------------------------------------------------
// Kernel 1: one WAVE per row — butterfly reduce, fp8 quantize. (unchanged)
// ---------------------------------------------------------------------------
__global__ void __launch_bounds__(256) prep_kernel(
    const float* __restrict__ sq, const float* __restrict__ sp,
    const float* __restrict__ tq, const float* __restrict__ tp,
    int* __restrict__ qn, int* __restrict__ pn,
    float* __restrict__ ppq, float* __restrict__ ppp, float* __restrict__ ppd)
{
    const int wave = threadIdx.x >> 6;
    const int l    = threadIdx.x & 63;
    const int r    = blockIdx.x * 4 + wave;
    const size_t rb4 = (size_t)r * (D_DIM / 4);

    const float4* Q4 = (const float4*)sq + rb4;
    const float4* P4 = (const float4*)sp + rb4;
    const float4* A4 = (const float4*)tq + rb4;
    const float4* B4 = (const float4*)tp + rb4;

    float4 qv[4], pv[4];
    float sq2 = 0.f, sp2 = 0.f, dq = 0.f, dp = 0.f, qp = 0.f;
    #pragma unroll
    for (int j = 0; j < 4; ++j) {
        const int idx = j * 64 + l;
        float4 q = Q4[idx], p = P4[idx], a = A4[idx], b = B4[idx];
        qv[j] = q; pv[j] = p;
        sq2 += q.x*q.x + q.y*q.y + q.z*q.z + q.w*q.w;
        sp2 += p.x*p.x + p.y*p.y + p.z*p.z + p.w*p.w;
        float dx = q.x-a.x, dy = q.y-a.y, dz = q.z-a.z, dw = q.w-a.w;
        dq += dx*dx + dy*dy + dz*dz + dw*dw;
        dx = p.x-b.x; dy = p.y-b.y; dz = p.z-b.z; dw = p.w-b.w;
        dp += dx*dx + dy*dy + dz*dz + dw*dw;
        qp += q.x*p.x + q.y*p.y + q.z*p.z + q.w*p.w;
    }

    #pragma unroll
    for (int m = 1; m <= 32; m <<= 1) {
        sq2 += __shfl_xor(sq2, m);
        sp2 += __shfl_xor(sp2, m);
        dq  += __shfl_xor(dq, m);
        dp  += __shfl_xor(dp, m);
        qp  += __shfl_xor(qp, m);
    }

    const float rq = 1.0f / fmaxf(sqrtf(sq2), 1e-8f);
    const float rp = 1.0f / fmaxf(sqrtf(sp2), 1e-8f);

    if (l == 0) {
        ppq[r] = dq;
        ppp[r] = dp;
        ppd[r] = qp * rq * rp;
    }

    const float fq = rq * FP8_SCALE;
    const float fp = rp * FP8_SCALE;
    int* qrow = qn + (size_t)r * (D_DIM / 4);
    int* prow = pn + (size_t)r * (D_DIM / 4);
    #pragma unroll
    for (int j = 0; j < 4; ++j) {
        const int idx = j * 64 + l;
        int pk = __builtin_amdgcn_cvt_pk_fp8_f32(qv[j].x * fq, qv[j].y * fq, 0, false);
        pk     = __builtin_amdgcn_cvt_pk_fp8_f32(qv[j].z * fq, qv[j].w * fq, pk, true);
        qrow[idx] = pk;
        pk = __builtin_amdgcn_cvt_pk_fp8_f32(pv[j].x * fp, pv[j].y * fp, 0, false);
        pk = __builtin_amdgcn_cvt_pk_fp8_f32(pv[j].z * fp, pv[j].w * fp, pk, true);
        prow[idx] = pk;
    }
}

// ---------------------------------------------------------------------------
// Kernel 2: S = Qn @ Pn^T via MX-scaled fp8 MFMA 16x16x128, 256x256 tile,
// *** 4 waves (2M x 2N), each owning a 128x128 output patch ***.
//
// Rationale (r1-r6 accounting): with 8 waves @128x64 patches the block
// issues 192 ds_read_b128 per K-step (A 4x-redundant, B 2x) = ~3070 cy of
// LDS time vs 2210 cy of MFMA time -> LDS-read-bound at ~34% MfmaUtil no
// matter the schedule.  2x2 waves @128x128 cut reads to 128/step (A,B both
// 2x-redundant): LDS ~2050 cy < MFMA 2210 cy -> MFMA becomes pacing.
//
// Mechanics preserved from round 5 (best, 81.3 us): r5 LDS swizzle
// chunk = (2q)^r7 (r6's st_16x32 port tripled conflicts - reverted),
// counted-vmcnt staging ledger, counted-lgkm read-ahead with look-ahead
// groups in flight under MFMA clusters, 2 barriers/step, setprio around
// MFMA clusters.  Per-acc MFMA chain over t unchanged -> bit-identical.
// ---------------------------------------------------------------------------
union Frag { int8v v8; struct { int4v lo, hi; } h; };

__global__ void __launch_bounds__(256, 1) gemm_rowsum_kernel(
    const u8* __restrict__ Q, const u8* __restrict__ P,
    float* __restrict__ gpart)
{
    __shared__ u8 smA[2][256 * 128];   // 2 x 32 KiB, row stride 128 B
    __shared__ u8 smB[2][256 * 128];   // 2 x 32 KiB   (total 128 KiB)

    const int tid  = threadIdx.x;
    const int wave = tid >> 6;         // 0..3
    const int lane = tid & 63;
    const int wm   = wave >> 1;        // 0..1 : 128-row half of the tile
    const int wn   = wave & 1;         // 0..1 : 128-col half of the tile
    const int bm   = blockIdx.y;
    const int bn   = blockIdx.x;

    // staging: one global_load_lds per wave covers 8 rows x 128 B; a STAGE
    // call (256 threads) covers 32 rows.  LDS written linearly; 16B-chunk
    // XOR swizzle (r5 scheme) applied on the GLOBAL source address.
    const int srow   = tid >> 3;                    // 0..31 within a call
    const int schunk = (tid & 7) ^ (srow & 7);      // pre-swizzled 16B chunk
    const u8* Ag = Q + (size_t)(bm * 256 + srow) * D_DIM + schunk * 16;
    const u8* Bg = P + (size_t)(bn * 256 + srow) * D_DIM + schunk * 16;
    const int ldsw = wave * 1024;                   // wave's 8-row sub-chunk

#define STAGE_A(b, rbase, k0)                                                  \
    __builtin_amdgcn_global_load_lds(                                          \
        (const __attribute__((address_space(1))) void*)(Ag + (size_t)(rbase) * D_DIM + (k0)), \
        (__attribute__((address_space(3))) void*)(&smA[b][(rbase) * 128] + ldsw), 16, 0, 0)
#define STAGE_B(b, rbase, k0)                                                  \
    __builtin_amdgcn_global_load_lds(                                          \
        (const __attribute__((address_space(1))) void*)(Bg + (size_t)(rbase) * D_DIM + (k0)), \
        (__attribute__((address_space(3))) void*)(&smB[b][(rbase) * 128] + ldsw), 16, 0, 0)

// 16 vmem issues per call (8 A + 8 B), covering full 256-row A and B tiles
#define STAGE_ALL(b, k0)                                                       \
    STAGE_A(b, 0,   k0); STAGE_A(b, 32,  k0); STAGE_A(b, 64,  k0);             \
    STAGE_A(b, 96,  k0); STAGE_A(b, 128, k0); STAGE_A(b, 160, k0);             \
    STAGE_A(b, 192, k0); STAGE_A(b, 224, k0);                                  \
    STAGE_B(b, 0,   k0); STAGE_B(b, 32,  k0); STAGE_B(b, 64,  k0);             \
    STAGE_B(b, 96,  k0); STAGE_B(b, 128, k0); STAGE_B(b, 160, k0);             \
    STAGE_B(b, 192, k0); STAGE_B(b, 224, k0);

    // fragment addressing (r5 swizzle):
    // A frag (mi): row = wm*128 + mi*16 + rw; k-chunks 2q,2q+1 at slots ^r7
    const int quad = lane >> 4;
    const int rw   = lane & 15;
    const int r7   = lane & 7;
    const int off_lo = ((2 * quad) ^ r7) * 16;
    const int off_hi = ((2 * quad + 1) ^ r7) * 16;
    const int arow_base = (wm * 128 + rw) * 128;    // + mi*2048
    const int brow_base = (wn * 128 + rw) * 128;    // + ni*2048

    f32x4 acc[8][8];
    #pragma unroll
    for (int i = 0; i < 8; ++i)
        #pragma unroll
        for (int j = 0; j < 8; ++j)
            acc[i][j] = (f32x4){0.f, 0.f, 0.f, 0.f};

    // prologue: stage step 0 -> buf0, step 1 -> buf1 (32 vmem issues)
    STAGE_ALL(0, 0)
    STAGE_ALL(1, 128)

#define SB0 __builtin_amdgcn_sched_barrier(0);
#define WAITL(n) asm volatile("s_waitcnt lgkmcnt(" #n ")" ::: "memory"); SB0

#define READ_AF(mi)                                                            \
    af[mi].h.lo = *(const int4v*)(sA_ + arow_base + (mi) * 2048 + off_lo);     \
    af[mi].h.hi = *(const int4v*)(sA_ + arow_base + (mi) * 2048 + off_hi);
#define READ_BF(ni)                                                            \
    bf[ni].h.lo = *(const int4v*)(sB_ + brow_base + (ni) * 2048 + off_lo);     \
    bf[ni].h.hi = *(const int4v*)(sB_ + brow_base + (ni) * 2048 + off_hi);

#define MFMA1(mi, ni)                                                          \
    acc[mi][ni] = __builtin_amdgcn_mfma_scale_f32_16x16x128_f8f6f4(            \
        af[mi].v8, bf[ni].v8, acc[mi][ni],                                     \
        0, 0, 0, 0x7f7f7f7f, 0, 0x7f7f7f7f);

#define KSTEP(t, DO_T2, VMN)                                                   \
  {                                                                            \
    constexpr int cur = (t) & 1;                                               \
    const u8* sA_ = &smA[cur][0];                                              \
    const u8* sB_ = &smB[cur][0];                                              \
    Frag af[8], bf[8];                                                         \
    /* entry: retire this step's 16 staging loads; next step's stay out */     \
    asm volatile("s_waitcnt vmcnt(" #VMN ")" ::: "memory");                    \
    __builtin_amdgcn_s_barrier();                                              \
    SB0                                                                        \
    /* R0 (8 b128) */                                                          \
    READ_BF(0) READ_BF(1) READ_AF(0) READ_AF(1)                                \
    SB0                                                                        \
    /* R1 (8) */                                                               \
    READ_AF(2) READ_AF(3) READ_BF(2) READ_BF(3)                                \
    WAITL(8)   /* R0 done, R1 in flight */                                     \
    __builtin_amdgcn_s_setprio(1);                                             \
    MFMA1(0, 0) MFMA1(0, 1) MFMA1(1, 0) MFMA1(1, 1)                            \
    __builtin_amdgcn_s_setprio(0);                                             \
    /* R2 (8) */                                                               \
    READ_AF(4) READ_AF(5) READ_BF(4) READ_BF(5)                                \
    WAITL(8)   /* R1 done, R2 in flight */                                     \
    __builtin_amdgcn_s_setprio(1);                                             \
    MFMA1(2, 0) MFMA1(2, 1) MFMA1(3, 0) MFMA1(3, 1)                            \
    MFMA1(0, 2) MFMA1(0, 3) MFMA1(1, 2) MFMA1(1, 3)                            \
    MFMA1(2, 2) MFMA1(2, 3) MFMA1(3, 2) MFMA1(3, 3)                            \
    __builtin_amdgcn_s_setprio(0);                                             \
    /* R3 (8) */                                                               \
    READ_AF(6) READ_AF(7) READ_BF(6) READ_BF(7)                                \
    WAITL(8)   /* R2 done, R3 in flight */                                     \
    __builtin_amdgcn_s_setprio(1);                                             \
    MFMA1(4, 0) MFMA1(4, 1) MFMA1(4, 2) MFMA1(4, 3)                            \
    MFMA1(5, 0) MFMA1(5, 1) MFMA1(5, 2) MFMA1(5, 3)                            \
    MFMA1(0, 4) MFMA1(0, 5) MFMA1(1, 4) MFMA1(1, 5)                            \
    MFMA1(2, 4) MFMA1(2, 5) MFMA1(3, 4) MFMA1(3, 5)                            \
    MFMA1(4, 4) MFMA1(4, 5) MFMA1(5, 4) MFMA1(5, 5)                            \
    __builtin_amdgcn_s_setprio(0);                                             \
    WAITL(0)   /* R3 done: all reads of buf[cur] complete */                   \
    __builtin_amdgcn_s_barrier();                                              \
    SB0                                                                        \
    /* restage buf[cur] for step t+2, then the remaining 28 MFMAs */           \
    if (DO_T2) { STAGE_ALL(cur, ((t) + 2) * 128) }                             \
    __builtin_amdgcn_s_setprio(1);                                             \
    MFMA1(6, 0) MFMA1(6, 1) MFMA1(6, 2) MFMA1(6, 3)                            \
    MFMA1(6, 4) MFMA1(6, 5) MFMA1(6, 6) MFMA1(6, 7)                            \
    MFMA1(7, 0) MFMA1(7, 1) MFMA1(7, 2) MFMA1(7, 3)                            \
    MFMA1(7, 4) MFMA1(7, 5) MFMA1(7, 6) MFMA1(7, 7)                            \
    MFMA1(0, 6) MFMA1(0, 7) MFMA1(1, 6) MFMA1(1, 7)                            \
    MFMA1(2, 6) MFMA1(2, 7) MFMA1(3, 6) MFMA1(3, 7)                            \
    MFMA1(4, 6) MFMA1(4, 7) MFMA1(5, 6) MFMA1(5, 7)                            \
    __builtin_amdgcn_s_setprio(0);                                             \
  }

    KSTEP(0, true,  16)
    KSTEP(1, true,  16)
    KSTEP(2, true,  16)
    KSTEP(3, true,  16)
    KSTEP(4, true,  16)
    KSTEP(5, true,  16)
    KSTEP(6, false, 16)
    KSTEP(7, false, 0)

#undef KSTEP
#undef MFMA1
#undef READ_AF
#undef READ_BF
#undef WAITL
#undef SB0
#undef STAGE_ALL
#undef STAGE_A
#undef STAGE_B

    // epilogue: per-row sum of exp over the wave's two 64-col slices.
    // C/D layout (shape-determined): col = lane&15, row = quad*4 + reg
    float esum[2][8][4];
    #pragma unroll
    for (int h = 0; h < 2; ++h)
        #pragma unroll
        for (int mi = 0; mi < 8; ++mi)
            #pragma unroll
            for (int r = 0; r < 4; ++r) {
                float s = 0.f;
                #pragma unroll
                for (int ni = 0; ni < 4; ++ni)
                    s += __expf(acc[mi][h * 4 + ni][r] * ACC_UNSCALE);
                esum[h][mi][r] = s;
            }
    #pragma unroll
    for (int m = 1; m <= 8; m <<= 1)
        #pragma unroll
        for (int h = 0; h < 2; ++h)
            #pragma unroll
            for (int mi = 0; mi < 8; ++mi)
                #pragma unroll
                for (int r = 0; r < 4; ++r)
                    esum[h][mi][r] += __shfl_xor(esum[h][mi][r], m);

    // slice index = global_col / 64 = bn*4 + wn*2 + h
    if (rw == 0) {
        #pragma unroll
        for (int h = 0; h < 2; ++h) {
            float* dst = gpart + (size_t)(bn * 4 + wn * 2 + h) * B_ROWS
                       + bm * 256 + wm * 128;
            #pragma unroll
            for (int mi = 0; mi < 8; ++mi)
                #pragma unroll
                for (int r = 0; r < 4; ++r)
                    dst[mi * 16 + quad * 4 + r] = esum[h][mi][r];
        }
    }
}

// ---------------------------------------------------------------------------
// Kernel 3: per-row sum of 128 gpart slices -> log; fold in the three
// pp-array reductions; one float4 partial per block. (unchanged)
// ---------------------------------------------------------------------------
__global__ void __launch_bounds__(256) reduce_kernel(
    const float* __restrict__ gpart,
    const float* __restrict__ ppq, const float* __restrict__ ppp,
    const float* __restrict__ ppd, float4* __restrict__ bpart)
{
    const int t = threadIdx.x;
    const int r = blockIdx.x * 256 + t;
    float s = 0.f;
    #pragma unroll 8
    for (int j = 0; j < 128; ++j) s += gpart[(size_t)j * B_ROWS + r];
    float ls = logf(s);
    float v2 = ppq[r], v3 = ppp[r], v4 = ppd[r];
    #pragma unroll
    for (int m = 1; m <= 32; m <<= 1) {
        ls += __shfl_xor(ls, m);
        v2 += __shfl_xor(v2, m);
        v3 += __shfl_xor(v3, m);
        v4 += __shfl_xor(v4, m);
    }
    __shared__ float red[4][4];
    if ((t & 63) == 0) {
        red[t >> 6][0] = ls; red[t >> 6][1] = v2;
        red[t >> 6][2] = v3; red[t >> 6][3] = v4;
    }
    __syncthreads();
    if (t == 0) {
        float4 o;
        o.x = red[0][0] + red[1][0] + red[2][0] + red[3][0];
        o.y = red[0][1] + red[1][1] + red[2][1] + red[3][1];
        o.z = red[0][2] + red[1][2] + red[2][2] + red[3][2];
        o.w = red[0][3] + red[1][3] + red[2][3] + red[3][3];
        bpart[blockIdx.x] = o;
    }
}

// ---------------------------------------------------------------------------
// Kernel 4: final scalar combine (1 wave, 32 float4 partials) (unchanged)
// ---------------------------------------------------------------------------
__global__ void __launch_bounds__(64) finalize_kernel(
    const float4* __restrict__ bpart, float* __restrict__ out)
{
    const int t = threadIdx.x;
    float4 v = (t < 32) ? bpart[t] : (float4){0.f, 0.f, 0.f, 0.f};
    #pragma unroll
    for (int m = 1; m <= 16; m <<= 1) {
        v.x += __shfl_xor(v.x, m);
        v.y += __shfl_xor(v.y, m);
        v.z += __shfl_xor(v.z, m);
        v.w += __shfl_xor(v.w, m);
    }
    if (t == 0) {
        const float inv_bd = 1.0f / ((float)B_ROWS * (float)D_DIM);
        float distill   = 0.5f * (v.y + v.z) * inv_bd;
        float retrieval = (v.x - v.w) / (float)B_ROWS;
        out[0] = 0.5f * distill + 0.5f * retrieval;
    }
}

extern "C" void kernel_launch(void* const* d_in, const int* in_sizes, int n_in,
                              void* d_out, int out_size, void* d_ws, size_t ws_size,
                              hipStream_t stream) {
    const float* sq = (const float*)d_in[0];
    const float* sp = (const float*)d_in[1];
    const float* tq = (const float*)d_in[2];
    const float* tp = (const float*)d_in[3];

    char* ws = (char*)d_ws;
    float*  ppq   = (float*)(ws);
    float*  ppp   = (float*)(ws + 32768);
    float*  ppd   = (float*)(ws + 65536);
    float4* bpart = (float4*)(ws + 98304);
    float*  gpart = (float*)(ws + 131072);                        // 4 MiB
    int*    qn    = (int*)(ws + 131072 + (size_t)128 * B_ROWS * 4);
    int*    pn    = (int*)((char*)qn + (size_t)B_ROWS * D_DIM);

    prep_kernel<<<B_ROWS / 4, 256, 0, stream>>>(sq, sp, tq, tp, qn, pn, ppq, ppp, ppd);
    gemm_rowsum_kernel<<<dim3(32, 32), 256, 0, stream>>>((const u8*)qn, (const u8*)pn, gpart);
    reduce_kernel<<<32, 256, 0, stream>>>(gpart, ppq, ppp, ppd, bpart);
    finalize_kernel<<<1, 64, 0, stream>>>(bpart, (float*)d_out);
}

// Round 8
// 230.429 us; speedup vs baseline: 1.1785x; 1.1785x over previous
//
#include <hip/hip_runtime.h>
#include <hip/hip_bf16.h>

typedef unsigned short u16;
typedef unsigned char u8;
typedef float f32x4 __attribute__((ext_vector_type(4)));
typedef int int4v __attribute__((ext_vector_type(4)));
typedef int int8v __attribute__((ext_vector_type(8)));

#define B_ROWS 8192
#define D_DIM  1024
#define FP8_SCALE 16.0f          // store x*16 in e4m3; acc = 256 * s_true
#define ACC_UNSCALE (1.0f/256.0f)

// ---------------------------------------------------------------------------
// Workspace layout (bytes):
//   [0,      32768)   ppq[8192]   per-row MSE(q) partial
//   [32768,  65536)   ppp[8192]   per-row MSE(p) partial
//   [65536,  98304)   ppd[8192]   per-row diag cosine (exact fp32)
//   [98304,  98816)   bpart[32][4] per-reduce-block partials
//   [131072, +4MiB)   gpart[128][8192]  per-64-col-slice row exp-sum partials
//   [+4MiB,  +8MiB)   qn fp8 [8192][1024]   (x16 pre-scaled e4m3)
//   [+8MiB,  ...)     pn fp8 [8192][1024]
// ---------------------------------------------------------------------------

// ---------------------------------------------------------------------------
// Kernel 1: one WAVE per row — butterfly reduce, fp8 quantize. (unchanged)
// ---------------------------------------------------------------------------
__global__ void __launch_bounds__(256) prep_kernel(
    const float* __restrict__ sq, const float* __restrict__ sp,
    const float* __restrict__ tq, const float* __restrict__ tp,
    int* __restrict__ qn, int* __restrict__ pn,
    float* __restrict__ ppq, float* __restrict__ ppp, float* __restrict__ ppd)
{
    const int wave = threadIdx.x >> 6;
    const int l    = threadIdx.x & 63;
    const int r    = blockIdx.x * 4 + wave;
    const size_t rb4 = (size_t)r * (D_DIM / 4);

    const float4* Q4 = (const float4*)sq + rb4;
    const float4* P4 = (const float4*)sp + rb4;
    const float4* A4 = (const float4*)tq + rb4;
    const float4* B4 = (const float4*)tp + rb4;

    float4 qv[4], pv[4];
    float sq2 = 0.f, sp2 = 0.f, dq = 0.f, dp = 0.f, qp = 0.f;
    #pragma unroll
    for (int j = 0; j < 4; ++j) {
        const int idx = j * 64 + l;
        float4 q = Q4[idx], p = P4[idx], a = A4[idx], b = B4[idx];
        qv[j] = q; pv[j] = p;
        sq2 += q.x*q.x + q.y*q.y + q.z*q.z + q.w*q.w;
        sp2 += p.x*p.x + p.y*p.y + p.z*p.z + p.w*p.w;
        float dx = q.x-a.x, dy = q.y-a.y, dz = q.z-a.z, dw = q.w-a.w;
        dq += dx*dx + dy*dy + dz*dz + dw*dw;
        dx = p.x-b.x; dy = p.y-b.y; dz = p.z-b.z; dw = p.w-b.w;
        dp += dx*dx + dy*dy + dz*dz + dw*dw;
        qp += q.x*p.x + q.y*p.y + q.z*p.z + q.w*p.w;
    }

    #pragma unroll
    for (int m = 1; m <= 32; m <<= 1) {
        sq2 += __shfl_xor(sq2, m);
        sp2 += __shfl_xor(sp2, m);
        dq  += __shfl_xor(dq, m);
        dp  += __shfl_xor(dp, m);
        qp  += __shfl_xor(qp, m);
    }

    const float rq = 1.0f / fmaxf(sqrtf(sq2), 1e-8f);
    const float rp = 1.0f / fmaxf(sqrtf(sp2), 1e-8f);

    if (l == 0) {
        ppq[r] = dq;
        ppp[r] = dp;
        ppd[r] = qp * rq * rp;
    }

    const float fq = rq * FP8_SCALE;
    const float fp = rp * FP8_SCALE;
    int* qrow = qn + (size_t)r * (D_DIM / 4);
    int* prow = pn + (size_t)r * (D_DIM / 4);
    #pragma unroll
    for (int j = 0; j < 4; ++j) {
        const int idx = j * 64 + l;
        int pk = __builtin_amdgcn_cvt_pk_fp8_f32(qv[j].x * fq, qv[j].y * fq, 0, false);
        pk     = __builtin_amdgcn_cvt_pk_fp8_f32(qv[j].z * fq, qv[j].w * fq, pk, true);
        qrow[idx] = pk;
        pk = __builtin_amdgcn_cvt_pk_fp8_f32(pv[j].x * fp, pv[j].y * fp, 0, false);
        pk = __builtin_amdgcn_cvt_pk_fp8_f32(pv[j].z * fp, pv[j].w * fp, pk, true);
        prow[idx] = pk;
    }
}

// ---------------------------------------------------------------------------
// Kernel 2: S = Qn @ Pn^T via MX-scaled fp8 MFMA 16x16x128.
// *** 128x128 tile, 4 waves (2x2, 64x64 patch), single-buffer 32 KiB LDS,
//     3 blocks/CU (m97 regime) ***
//
// Rationale (r1-r7 accounting): one 8-wave block/CU runs DS (3072 cy) and
// MFMA (2208 cy) strictly in SUM — lockstep barriers defeat every intra-
// block schedule (5 variants, all ~6100 cy/step).  The register file
// (512/lane/SIMD) forbids bigger patches (r7 spill disaster) or frag
// double-buffering.  The remaining lever is CROSS-BLOCK desync: 3 small
// independent blocks/CU overlap one block's DS burst with another's MFMA
// burst (measured m97/m114 mechanism; also the regime where setprio pays).
// Cost: 1.33x LDS reads per FLOP — wins if overlap > 1.5x.
//
// Per wave/step: 16 ds_read_b128, 16 MFMA; acc 64 + frags 64 regs.
// __launch_bounds__(256,3) caps at 170 regs -> no spill, 12 waves/CU.
// r5 LDS swizzle (chunk = 2q^r7) kept.  Per-element k-chain order over t
// unchanged -> output bit-identical to r5.
// ---------------------------------------------------------------------------
union Frag { int8v v8; struct { int4v lo, hi; } h; };

__global__ void __launch_bounds__(256, 3) gemm_rowsum_kernel(
    const u8* __restrict__ Q, const u8* __restrict__ P,
    float* __restrict__ gpart)
{
    __shared__ u8 smA[128 * 128];   // 16 KiB, row stride 128 B
    __shared__ u8 smB[128 * 128];   // 16 KiB   (total 32 KiB)

    const int tid  = threadIdx.x;
    const int wave = tid >> 6;         // 0..3
    const int lane = tid & 63;
    const int wm   = wave >> 1;        // 0..1 : 64-row half of the tile
    const int wn   = wave & 1;         // 0..1 : 64-col half of the tile
    const int bm   = blockIdx.y;
    const int bn   = blockIdx.x;

    // staging: one STAGE call (256 threads) covers 32 rows x 128 B.
    // LDS written linearly; 16B-chunk XOR swizzle (r5 scheme) applied on
    // the GLOBAL source address; read side XORs with row&7.
    const int srow   = tid >> 3;                    // 0..31 within a call
    const int schunk = (tid & 7) ^ (srow & 7);      // pre-swizzled 16B chunk
    const u8* Ag = Q + (size_t)(bm * 128 + srow) * D_DIM + schunk * 16;
    const u8* Bg = P + (size_t)(bn * 128 + srow) * D_DIM + schunk * 16;
    const int ldsw = wave * 1024;                   // wave's 8-row sub-chunk

#define STAGE_A(rbase, k0)                                                     \
    __builtin_amdgcn_global_load_lds(                                          \
        (const __attribute__((address_space(1))) void*)(Ag + (size_t)(rbase) * D_DIM + (k0)), \
        (__attribute__((address_space(3))) void*)(smA + (rbase) * 128 + ldsw), 16, 0, 0)
#define STAGE_B(rbase, k0)                                                     \
    __builtin_amdgcn_global_load_lds(                                          \
        (const __attribute__((address_space(1))) void*)(Bg + (size_t)(rbase) * D_DIM + (k0)), \
        (__attribute__((address_space(3))) void*)(smB + (rbase) * 128 + ldsw), 16, 0, 0)

// 8 vmem issues per call, covering the full 128-row A and B tiles
#define STAGE_ALL(k0)                                                          \
    STAGE_A(0, k0); STAGE_A(32, k0); STAGE_A(64, k0); STAGE_A(96, k0);         \
    STAGE_B(0, k0); STAGE_B(32, k0); STAGE_B(64, k0); STAGE_B(96, k0);

    // fragment addressing (r5 swizzle):
    // A frag (mi): row = wm*64 + mi*16 + rw; k-chunks 2q,2q+1 at slots ^r7
    const int quad = lane >> 4;
    const int rw   = lane & 15;
    const int r7   = lane & 7;
    const int off_lo = ((2 * quad) ^ r7) * 16;
    const int off_hi = ((2 * quad + 1) ^ r7) * 16;
    const int arow_base = (wm * 64 + rw) * 128;     // + mi*2048
    const int brow_base = (wn * 64 + rw) * 128;     // + ni*2048

    f32x4 acc[4][4];
    #pragma unroll
    for (int i = 0; i < 4; ++i)
        #pragma unroll
        for (int j = 0; j < 4; ++j)
            acc[i][j] = (f32x4){0.f, 0.f, 0.f, 0.f};

    // prologue: stage step 0
    STAGE_ALL(0)

#define SB0 __builtin_amdgcn_sched_barrier(0);

#define MFMA1(mi, ni)                                                          \
    acc[mi][ni] = __builtin_amdgcn_mfma_scale_f32_16x16x128_f8f6f4(            \
        af[mi].v8, bf[ni].v8, acc[mi][ni],                                     \
        0, 0, 0, 0x7f7f7f7f, 0, 0x7f7f7f7f);

#define KSTEP(t, DO_NEXT)                                                      \
  {                                                                            \
    Frag af[4], bf[4];                                                         \
    /* stage(t) landed (only our 8 loads outstanding) */                       \
    asm volatile("s_waitcnt vmcnt(0)" ::: "memory");                           \
    __builtin_amdgcn_s_barrier();                                              \
    SB0                                                                        \
    /* 16 b128 reads: lo group then hi group */                                \
    _Pragma("unroll")                                                          \
    for (int mi = 0; mi < 4; ++mi)                                             \
      af[mi].h.lo = *(const int4v*)(smA + arow_base + mi * 2048 + off_lo);     \
    _Pragma("unroll")                                                          \
    for (int ni = 0; ni < 4; ++ni)                                             \
      bf[ni].h.lo = *(const int4v*)(smB + brow_base + ni * 2048 + off_lo);     \
    SB0                                                                        \
    _Pragma("unroll")                                                          \
    for (int mi = 0; mi < 4; ++mi)                                             \
      af[mi].h.hi = *(const int4v*)(smA + arow_base + mi * 2048 + off_hi);     \
    _Pragma("unroll")                                                          \
    for (int ni = 0; ni < 4; ++ni)                                             \
      bf[ni].h.hi = *(const int4v*)(smB + brow_base + ni * 2048 + off_hi);     \
    asm volatile("s_waitcnt lgkmcnt(0)" ::: "memory");                         \
    SB0                                                                        \
    __builtin_amdgcn_s_barrier();   /* all waves done reading -> WAR safe */   \
    SB0                                                                        \
    /* restage for t+1 (async, retired at next entry), then 16 MFMAs */        \
    if (DO_NEXT) { STAGE_ALL(((t) + 1) * 128) }                                \
    __builtin_amdgcn_s_setprio(1);                                             \
    MFMA1(0, 0) MFMA1(0, 1) MFMA1(1, 0) MFMA1(1, 1)                            \
    MFMA1(0, 2) MFMA1(0, 3) MFMA1(1, 2) MFMA1(1, 3)                            \
    MFMA1(2, 0) MFMA1(2, 1) MFMA1(3, 0) MFMA1(3, 1)                            \
    MFMA1(2, 2) MFMA1(2, 3) MFMA1(3, 2) MFMA1(3, 3)                            \
    __builtin_amdgcn_s_setprio(0);                                             \
  }

    KSTEP(0, true)
    KSTEP(1, true)
    KSTEP(2, true)
    KSTEP(3, true)
    KSTEP(4, true)
    KSTEP(5, true)
    KSTEP(6, true)
    KSTEP(7, false)

#undef KSTEP
#undef MFMA1
#undef SB0
#undef STAGE_ALL
#undef STAGE_A
#undef STAGE_B

    // epilogue: per-row sum of exp over this wave's 64 columns.
    // C/D layout (shape-determined): col = lane&15, row = quad*4 + reg
    float esum[4][4];
    #pragma unroll
    for (int mi = 0; mi < 4; ++mi)
        #pragma unroll
        for (int r = 0; r < 4; ++r) {
            float s = 0.f;
            #pragma unroll
            for (int ni = 0; ni < 4; ++ni)
                s += __expf(acc[mi][ni][r] * ACC_UNSCALE);
            esum[mi][r] = s;
        }
    #pragma unroll
    for (int m = 1; m <= 8; m <<= 1)
        #pragma unroll
        for (int mi = 0; mi < 4; ++mi)
            #pragma unroll
            for (int r = 0; r < 4; ++r)
                esum[mi][r] += __shfl_xor(esum[mi][r], m);

    // slice index = global_col / 64 = bn*2 + wn
    if (rw == 0) {
        float* dst = gpart + (size_t)(bn * 2 + wn) * B_ROWS
                   + bm * 128 + wm * 64;
        #pragma unroll
        for (int mi = 0; mi < 4; ++mi)
            #pragma unroll
            for (int r = 0; r < 4; ++r)
                dst[mi * 16 + quad * 4 + r] = esum[mi][r];
    }
}

// ---------------------------------------------------------------------------
// Kernel 3: per-row sum of 128 gpart slices -> log; fold in the three
// pp-array reductions; one float4 partial per block. (unchanged)
// ---------------------------------------------------------------------------
__global__ void __launch_bounds__(256) reduce_kernel(
    const float* __restrict__ gpart,
    const float* __restrict__ ppq, const float* __restrict__ ppp,
    const float* __restrict__ ppd, float4* __restrict__ bpart)
{
    const int t = threadIdx.x;
    const int r = blockIdx.x * 256 + t;
    float s = 0.f;
    #pragma unroll 8
    for (int j = 0; j < 128; ++j) s += gpart[(size_t)j * B_ROWS + r];
    float ls = logf(s);
    float v2 = ppq[r], v3 = ppp[r], v4 = ppd[r];
    #pragma unroll
    for (int m = 1; m <= 32; m <<= 1) {
        ls += __shfl_xor(ls, m);
        v2 += __shfl_xor(v2, m);
        v3 += __shfl_xor(v3, m);
        v4 += __shfl_xor(v4, m);
    }
    __shared__ float red[4][4];
    if ((t & 63) == 0) {
        red[t >> 6][0] = ls; red[t >> 6][1] = v2;
        red[t >> 6][2] = v3; red[t >> 6][3] = v4;
    }
    __syncthreads();
    if (t == 0) {
        float4 o;
        o.x = red[0][0] + red[1][0] + red[2][0] + red[3][0];
        o.y = red[0][1] + red[1][1] + red[2][1] + red[3][1];
        o.z = red[0][2] + red[1][2] + red[2][2] + red[3][2];
        o.w = red[0][3] + red[1][3] + red[2][3] + red[3][3];
        bpart[blockIdx.x] = o;
    }
}

// ---------------------------------------------------------------------------
// Kernel 4: final scalar combine (1 wave, 32 float4 partials) (unchanged)
// ---------------------------------------------------------------------------
__global__ void __launch_bounds__(64) finalize_kernel(
    const float4* __restrict__ bpart, float* __restrict__ out)
{
    const int t = threadIdx.x;
    float4 v = (t < 32) ? bpart[t] : (float4){0.f, 0.f, 0.f, 0.f};
    #pragma unroll
    for (int m = 1; m <= 16; m <<= 1) {
        v.x += __shfl_xor(v.x, m);
        v.y += __shfl_xor(v.y, m);
        v.z += __shfl_xor(v.z, m);
        v.w += __shfl_xor(v.w, m);
    }
    if (t == 0) {
        const float inv_bd = 1.0f / ((float)B_ROWS * (float)D_DIM);
        float distill   = 0.5f * (v.y + v.z) * inv_bd;
        float retrieval = (v.x - v.w) / (float)B_ROWS;
        out[0] = 0.5f * distill + 0.5f * retrieval;
    }
}

extern "C" void kernel_launch(void* const* d_in, const int* in_sizes, int n_in,
                              void* d_out, int out_size, void* d_ws, size_t ws_size,
                              hipStream_t stream) {
    const float* sq = (const float*)d_in[0];
    const float* sp = (const float*)d_in[1];
    const float* tq = (const float*)d_in[2];
    const float* tp = (const float*)d_in[3];

    char* ws = (char*)d_ws;
    float*  ppq   = (float*)(ws);
    float*  ppp   = (float*)(ws + 32768);
    float*  ppd   = (float*)(ws + 65536);
    float4* bpart = (float4*)(ws + 98304);
    float*  gpart = (float*)(ws + 131072);                        // 4 MiB
    int*    qn    = (int*)(ws + 131072 + (size_t)128 * B_ROWS * 4);
    int*    pn    = (int*)((char*)qn + (size_t)B_ROWS * D_DIM);

    prep_kernel<<<B_ROWS / 4, 256, 0, stream>>>(sq, sp, tq, tp, qn, pn, ppq, ppp, ppd);
    gemm_rowsum_kernel<<<dim3(64, 64), 256, 0, stream>>>((const u8*)qn, (const u8*)pn, gpart);
    reduce_kernel<<<32, 256, 0, stream>>>(gpart, ppq, ppp, ppd, bpart);
    finalize_kernel<<<1, 64, 0, stream>>>(bpart, (float*)d_out);
}